// Round 7
// baseline (215.166 us; speedup 1.0000x reference)
//
#include <hip/hip_runtime.h>
#include <math.h>

#define EPS 1e-5f

typedef unsigned short ushort_t;
typedef __attribute__((ext_vector_type(8))) __bf16 bf16x8;
typedef __attribute__((ext_vector_type(4))) __bf16 bf16x4;
typedef __attribute__((ext_vector_type(4))) float f32x4;
typedef __attribute__((ext_vector_type(16))) float f32x16;

#define MFMA16(a, b, c) __builtin_amdgcn_mfma_f32_16x16x32_bf16(a, b, c, 0, 0, 0)
#define MFMA32(a, b, c) __builtin_amdgcn_mfma_f32_32x32x16_bf16(a, b, c, 0, 0, 0)

// 0.125 (attn scale) * log2(e): folded into Q at the QKV epilogue so the
// attention softmax runs directly in base-2 (v_exp_f32 = 2^x).
#define QSCALE2 0.18033688011112042f

__device__ __forceinline__ unsigned short f2bf(float f) {
  unsigned u = __float_as_uint(f);
  u += 0x7fffu + ((u >> 16) & 1u);
  return (unsigned short)(u >> 16);
}

__device__ __forceinline__ void gload16(const void* g, void* l) {
  __builtin_amdgcn_global_load_lds(
      (__attribute__((address_space(1))) void*)(g),
      (__attribute__((address_space(3))) void*)(l), 16, 0, 0);
}

// ---------------- fused cast f32 -> bf16 for all weights + q ----------------
__global__ __launch_bounds__(256) void cast_all_k(
    const float* __restrict__ wq, const float* __restrict__ wk,
    const float* __restrict__ wv, const float* __restrict__ wo,
    const float* __restrict__ w1, const float* __restrict__ w2,
    const float* __restrict__ q, ushort_t* __restrict__ wqkv,
    ushort_t* __restrict__ wob, ushort_t* __restrict__ w1b,
    ushort_t* __restrict__ w2b, ushort_t* __restrict__ qbf) {
  const int b = blockIdx.x;
  const float* src;
  ushort_t* dst;
  int idx;
  if (b < 2048) {
    const int s = b >> 9;
    src = (s == 0) ? wq : (s == 1) ? wk : (s == 2) ? wv : wo;
    dst = (s == 3) ? wob : wqkv + s * 1048576;
    idx = (b & 511) * 2048 + threadIdx.x * 8;
  } else if (b < 4096) {
    src = w1; dst = w1b; idx = (b - 2048) * 2048 + threadIdx.x * 8;
  } else if (b < 6144) {
    src = w2; dst = w2b; idx = (b - 4096) * 2048 + threadIdx.x * 8;
  } else {
    src = q; dst = qbf; idx = (b - 6144) * 2048 + threadIdx.x * 8;
  }
  float4 a = *(const float4*)(src + idx);
  float4 c = *(const float4*)(src + idx + 4);
  uint4 u;
  u.x = (unsigned)f2bf(a.x) | ((unsigned)f2bf(a.y) << 16);
  u.y = (unsigned)f2bf(a.z) | ((unsigned)f2bf(a.w) << 16);
  u.z = (unsigned)f2bf(c.x) | ((unsigned)f2bf(c.y) << 16);
  u.w = (unsigned)f2bf(c.z) | ((unsigned)f2bf(c.w) << 16);
  *(uint4*)(dst + idx) = u;
}

// ---------------- BN eval params (both BNs in one launch) ----------------
__global__ __launch_bounds__(256) void bnparam_k(
    const float* __restrict__ g1, const float* __restrict__ b1,
    const float* __restrict__ m1, const float* __restrict__ v1,
    const float* __restrict__ g2, const float* __restrict__ b2,
    const float* __restrict__ m2, const float* __restrict__ v2,
    float* __restrict__ sc1, float* __restrict__ sh1,
    float* __restrict__ sc2, float* __restrict__ sh2) {
  int i = blockIdx.x * 256 + threadIdx.x;
  if (i < 4096) {
    float s = g1[i] * rsqrtf(v1[i] + EPS);
    sc1[i] = s;
    sh1[i] = b1[i] - m1[i] * s;
  } else if (i < 5120) {
    int j = i - 4096;
    float s = g2[j] * rsqrtf(v2[j] + EPS);
    sc2[j] = s;
    sh2[j] = b2[j] - m2[j] * s;
  }
}

// ---------------- 2-phase GEMM, 32x32x16 MFMA  C[m,n]=sum_k A[m,k]W[n,k] -----
// Wave grid WM x WN, wave tile (32*TM32)x(32*TN32) as 32x32 frags, BK=64 (4
// k-steps of 16). Same STAGE/XOR-swizzle/sync structure as the proven 16x16
// template; only fragment indexing + epilogue layout change.
// C frag layout (m74/m101): col = lane&31, row = (r&3)+8*(r>>2)+4*(lane>>5).
// A/B frag: row(col) = lane&31, k = (lane>>5)*8 + e  -> granule s*2+(lane>>5).
template <int KDIM, int EPI, int TM32, int TN32, int WM, int WN, int NTHR, int GX, int GY>
__global__ __launch_bounds__(NTHR, 2) void gemm32(const ushort_t* __restrict__ A,
                                                  const ushort_t* __restrict__ W,
                                                  const float* __restrict__ p0,
                                                  const float* __restrict__ p1,
                                                  const float* __restrict__ p2,
                                                  float* __restrict__ outF,
                                                  ushort_t* __restrict__ outB) {
  constexpr int BM = 32 * TM32 * WM, BN = 32 * TN32 * WN;
  constexpr int LDS_STAGE = 2 * (BM + BN) * 128;
  constexpr int LDS_TR = (EPI == 0) ? 128 * 136 * 2 : 0;
  __shared__ alignas(16) char pool[(LDS_STAGE > LDS_TR) ? LDS_STAGE : LDS_TR];
  constexpr int LA = BM * 8 / NTHR;
  constexpr int LB = BN * 8 / NTHR;

  constexpr int NWG = GX * GY;
  const int id = blockIdx.x;
  const int pos = (id & 7) * (NWG / 8) + (id >> 3);
  const int grp = pos / (8 * GX);
  const int rem = pos % (8 * GX);
  const int by = grp * 8 + (rem & 7);
  const int bx = rem >> 3;
  const int bm = by * BM, bn = bx * BN;

  const int tid = threadIdx.x;
  const int lane = tid & 63;
  const int wid = tid >> 6;
  const int wr = wid / WN, wc = wid % WN;
  const int c32 = lane & 31;
  const int l5 = lane >> 5;
  const int wrow = wr * (32 * TM32), wcol = wc * (32 * TN32);

  const char* Ag0 = (const char*)(A + (size_t)bm * KDIM);
  const char* Bg0 = (const char*)(W + (size_t)bn * KDIM);

#define STAGE(bufi, t_)                                                        \
  do {                                                                         \
    const char* Ag = Ag0 + (size_t)(t_)*128;                                   \
    const char* Bg = Bg0 + (size_t)(t_)*128;                                   \
    char* Ab = pool + (bufi) * (BM * 128);                                     \
    char* Bb = pool + 2 * BM * 128 + (bufi) * (BN * 128);                      \
    _Pragma("unroll") for (int li = 0; li < LA; ++li) {                        \
      const int f = li * NTHR + tid;                                           \
      const int row = f >> 3;                                                  \
      const int gl = (f & 7) ^ (row & 7);                                      \
      gload16(Ag + (size_t)row * (KDIM * 2) + gl * 16,                         \
              Ab + (li * NTHR + wid * 64) * 16);                               \
    }                                                                          \
    _Pragma("unroll") for (int li = 0; li < LB; ++li) {                        \
      const int f = li * NTHR + tid;                                           \
      const int row = f >> 3;                                                  \
      const int gl = (f & 7) ^ (row & 7);                                      \
      gload16(Bg + (size_t)row * (KDIM * 2) + gl * 16,                         \
              Bb + (li * NTHR + wid * 64) * 16);                               \
    }                                                                          \
  } while (0)

  f32x16 acc[TM32][TN32];
#pragma unroll
  for (int i = 0; i < TM32; ++i)
#pragma unroll
    for (int j = 0; j < TN32; ++j)
#pragma unroll
      for (int r = 0; r < 16; ++r) acc[i][j][r] = 0.f;

  STAGE(0, 0);
  asm volatile("s_waitcnt vmcnt(0)" ::: "memory");
  __builtin_amdgcn_s_barrier();

  constexpr int NT = KDIM / 64;
  for (int t = 0; t < NT; ++t) {
    const int b = t & 1;
    if (t + 1 < NT) STAGE(b ^ 1, t + 1);  // prefetch flies under compute
    const char* Ac = pool + b * (BM * 128);
    const char* Bc = pool + 2 * BM * 128 + b * (BN * 128);
#pragma unroll
    for (int s = 0; s < 4; ++s) {
      bf16x8 bfv[TN32];
#pragma unroll
      for (int nf = 0; nf < TN32; ++nf) {
        const int row = wcol + nf * 32 + c32;
        bfv[nf] = *(const bf16x8*)(Bc + row * 128 + (((s * 2 + l5) ^ (row & 7)) * 16));
      }
#pragma unroll
      for (int mf = 0; mf < TM32; ++mf) {
        const int row = wrow + mf * 32 + c32;
        bf16x8 af = *(const bf16x8*)(Ac + row * 128 + (((s * 2 + l5) ^ (row & 7)) * 16));
#pragma unroll
        for (int nf = 0; nf < TN32; ++nf) acc[mf][nf] = MFMA32(af, bfv[nf], acc[mf][nf]);
      }
    }
    asm volatile("s_waitcnt vmcnt(0)" ::: "memory");
    __builtin_amdgcn_s_barrier();
  }
#undef STAGE

  if constexpr (EPI == 0) {
    if (bn < 2048) {
#pragma unroll
      for (int mf = 0; mf < TM32; ++mf) {
#pragma unroll
        for (int nf = 0; nf < TN32; ++nf) {
#pragma unroll
          for (int r = 0; r < 16; ++r) {
            const int m = bm + wrow + mf * 32 + (r & 3) + 8 * (r >> 2) + 4 * l5;
            const int n = bn + wcol + nf * 32 + c32;
            const int sel = n >> 10;
            const int nl = n & 1023;
            float v = acc[mf][nf][r] + ((sel == 0) ? p0[nl] : p1[nl]);
            if (sel == 0) v *= QSCALE2;
            const int b_ = m >> 10, tok = m & 1023;
            const int h_ = nl >> 6, d_ = nl & 63;
            outB[(size_t)sel * 4194304 + (((size_t)(b_ * 16 + h_) * 1024 + tok) * 64 + d_)] =
                f2bf(v);
          }
        }
      }
    } else {
      __syncthreads();
      ushort_t* T = (ushort_t*)pool;  // [128 n][136 m-pad]
#pragma unroll
      for (int mf = 0; mf < TM32; ++mf) {
#pragma unroll
        for (int nf = 0; nf < TN32; ++nf) {
          const int nl = wcol + nf * 32 + c32;
          const float bias = p2[(bn & 1023) + nl];
#pragma unroll
          for (int rq = 0; rq < 4; ++rq) {
            const int ml = wrow + mf * 32 + 8 * rq + 4 * l5;
            bf16x4 pw;
#pragma unroll
            for (int j = 0; j < 4; ++j) pw[j] = (__bf16)(acc[mf][nf][rq * 4 + j] + bias);
            *(bf16x4*)(T + nl * 136 + ml) = pw;
          }
        }
      }
      __syncthreads();
      const int b_ = bm >> 10;
      const int tokb = bm & 1023;
#pragma unroll
      for (int it = 0; it < 8; ++it) {
        const int g = it * 256 + tid;
        const int nl = g >> 4;
        const int m0 = (g & 15) * 8;
        bf16x8 v = *(const bf16x8*)(T + nl * 136 + m0);
        const int nloc = (bn - 2048) + nl;
        const int h_ = nloc >> 6, d_ = nloc & 63;
        *(bf16x8*)(outB + 8388608 + (((size_t)(b_ * 16 + h_) * 64 + d_) << 10) + tokb + m0) = v;
      }
    }
  } else {
#pragma unroll
    for (int mf = 0; mf < TM32; ++mf) {
#pragma unroll
      for (int nf = 0; nf < TN32; ++nf) {
        const int n = bn + wcol + nf * 32 + c32;
#pragma unroll
        for (int r = 0; r < 16; ++r) {
          const int m = bm + wrow + mf * 32 + (r & 3) + 8 * (r >> 2) + 4 * l5;
          float v = acc[mf][nf][r];
          if constexpr (EPI == 1) {
            v += p0[n] + p1[(size_t)m * 1024 + n];
            outF[(size_t)m * 1024 + n] = v;
          } else if constexpr (EPI == 2) {
            // tanh-form GELU (|err| vs exact erf <= ~3e-3)
            float tt = v * p0[n] + p1[n];
            float u = tt * (0.7978845608f + 0.0356774081f * tt * tt);
            float e = exp2f(u * 2.8853900818f);  // e^{2u}
            float ge = tt * (1.f - 1.f / (e + 1.f));
            outB[(size_t)m * 4096 + n] = f2bf(ge);
          } else {
            outF[(size_t)m * 1024 + n] = v * p0[n] + p1[n];
          }
        }
      }
    }
  }
}

// ---------------- flash attention (swapped QK^T, LDS-staged K/V, dbuf) -------
__global__ __launch_bounds__(512) void attn_k(const ushort_t* __restrict__ qp,
                                              const ushort_t* __restrict__ kp,
                                              const ushort_t* __restrict__ vt,
                                              ushort_t* __restrict__ aout) {
  __shared__ ushort_t Kt[2][4096];
  __shared__ ushort_t Vt[2][4096];
  __shared__ ushort_t P[8][16][72];
  const int tid = threadIdx.x;
  const int lane = tid & 63;
  const int wid = tid >> 6;
  const int fr = lane & 15;
  const int kg = lane >> 4;
  const int id = blockIdx.x;
  const int slot = id >> 3;
  const int bh = ((id & 7) << 3) | (slot >> 3);  // 8 heads per XCD chunk
  const int qc = slot & 7;
  const int b_ = bh >> 4, h_ = bh & 15;

  const size_t base = (size_t)bh << 10;
  const int qrow = qc * 128 + wid * 16 + fr;
  bf16x8 qf0 = *(const bf16x8*)(qp + ((base + qrow) << 6) + kg * 8);
  bf16x8 qf1 = *(const bf16x8*)(qp + ((base + qrow) << 6) + 32 + kg * 8);

  const int srow = tid >> 3;
  const int sg16 = ((tid & 7) ^ (srow & 7)) * 16;
  const char* kTileB = (const char*)kp + ((size_t)bh << 17);
  const char* vTileB = (const char*)vt + ((size_t)bh << 17);
  const size_t koff = (size_t)srow * 128 + sg16;   // + kt*8192
  const size_t voff = (size_t)srow * 2048 + sg16;  // + kt*128

#define STAGE(bufi, kt_)                                                      \
  do {                                                                        \
    gload16(kTileB + (size_t)(kt_)*8192 + koff, (char*)Kt[bufi] + wid * 1024); \
    gload16(vTileB + (size_t)(kt_)*128 + voff, (char*)Vt[bufi] + wid * 1024);  \
  } while (0)

  f32x4 oacc[4];
#pragma unroll
  for (int d = 0; d < 4; ++d)
#pragma unroll
    for (int r = 0; r < 4; ++r) oacc[d][r] = 0.f;
  float mrun = -3.0e38f, lrun = 0.f;

  STAGE(0, 0);
  __syncthreads();

  for (int kt = 0; kt < 16; ++kt) {
    const int c = kt & 1;
    if (kt < 15) STAGE(c ^ 1, kt + 1);
    const char* Kc = (const char*)Kt[c];
    const char* Vc = (const char*)Vt[c];

    f32x4 sacc[4];
#pragma unroll
    for (int nf = 0; nf < 4; ++nf)
#pragma unroll
      for (int r = 0; r < 4; ++r) sacc[nf][r] = 0.f;
    __builtin_amdgcn_s_setprio(1);
#pragma unroll
    for (int nf = 0; nf < 4; ++nf) {
      const int r_ = nf * 16 + fr;
      const char* kr = Kc + r_ * 128;
      bf16x8 kf0 = *(const bf16x8*)(kr + ((kg ^ (r_ & 7)) * 16));
      bf16x8 kf1 = *(const bf16x8*)(kr + (((kg + 4) ^ (r_ & 7)) * 16));
      sacc[nf] = MFMA16(kf0, qf0, sacc[nf]);
      sacc[nf] = MFMA16(kf1, qf1, sacc[nf]);
    }
    __builtin_amdgcn_s_setprio(0);
    float mx = sacc[0][0];
#pragma unroll
    for (int nf = 0; nf < 4; ++nf)
#pragma unroll
      for (int r = 0; r < 4; ++r) mx = fmaxf(mx, sacc[nf][r]);
    mx = fmaxf(mx, __shfl_xor(mx, 16));
    mx = fmaxf(mx, __shfl_xor(mx, 32));
    const float mn = fmaxf(mrun, mx);
    const float c_ = exp2f(mrun - mn);
    float rs = 0.f;
#pragma unroll
    for (int nf = 0; nf < 4; ++nf) {
      bf16x4 pw;
#pragma unroll
      for (int r = 0; r < 4; ++r) {
        float ev = exp2f(sacc[nf][r] - mn);
        rs += ev;
        pw[r] = (__bf16)ev;
      }
      *(bf16x4*)(&P[wid][fr][nf * 16 + kg * 4]) = pw;
    }
    rs += __shfl_xor(rs, 16);
    rs += __shfl_xor(rs, 32);
    lrun = lrun * c_ + rs;
    mrun = mn;
    float cb[4];
#pragma unroll
    for (int r = 0; r < 4; ++r) cb[r] = __shfl(c_, kg * 4 + r);
#pragma unroll
    for (int d = 0; d < 4; ++d)
#pragma unroll
      for (int r = 0; r < 4; ++r) oacc[d][r] *= cb[r];
    bf16x8 pa0 = *(const bf16x8*)(&P[wid][fr][kg * 8]);
    bf16x8 pa1 = *(const bf16x8*)(&P[wid][fr][32 + kg * 8]);
    __builtin_amdgcn_s_setprio(1);
#pragma unroll
    for (int df = 0; df < 4; ++df) {
      const int r_ = df * 16 + fr;
      const char* vr_ = Vc + r_ * 128;
      bf16x8 vf0 = *(const bf16x8*)(vr_ + ((kg ^ (r_ & 7)) * 16));
      bf16x8 vf1 = *(const bf16x8*)(vr_ + (((kg + 4) ^ (r_ & 7)) * 16));
      oacc[df] = MFMA16(pa0, vf0, oacc[df]);
      oacc[df] = MFMA16(pa1, vf1, oacc[df]);
    }
    __builtin_amdgcn_s_setprio(0);
    __syncthreads();
  }
#undef STAGE

  float linv[4];
#pragma unroll
  for (int r = 0; r < 4; ++r) linv[r] = 1.f / __shfl(lrun, kg * 4 + r);
#pragma unroll
  for (int df = 0; df < 4; ++df) {
#pragma unroll
    for (int r = 0; r < 4; ++r) {
      const int tok = qc * 128 + wid * 16 + kg * 4 + r;
      const int d_ = df * 16 + fr;
      aout[((size_t)(b_ * 1024 + tok) * 16 + h_) * 64 + d_] = f2bf(oacc[df][r] * linv[r]);
    }
  }
}

// ---------------- LayerNorm over rows of 1024 ----------------
template <int MODE>
__global__ __launch_bounds__(256) void ln_k(const float* __restrict__ in1,
                                            const float* __restrict__ in2,
                                            const float* __restrict__ g,
                                            const float* __restrict__ bt,
                                            float* __restrict__ outF,
                                            ushort_t* __restrict__ outB) {
  const int row = blockIdx.x;
  const int tid = threadIdx.x;
  const size_t off = (size_t)row * 1024 + tid * 4;
  float4 v = *(const float4*)(in1 + off);
  if (MODE == 1) {
    float4 u = *(const float4*)(in2 + off);
    v.x += u.x; v.y += u.y; v.z += u.z; v.w += u.w;
  }
  float s = v.x + v.y + v.z + v.w;
  float q = v.x * v.x + v.y * v.y + v.z * v.z + v.w * v.w;
#pragma unroll
  for (int o = 32; o > 0; o >>= 1) {
    s += __shfl_down(s, o);
    q += __shfl_down(q, o);
  }
  __shared__ float rs[4], rq[4], stat[2];
  const int wid = tid >> 6, lane = tid & 63;
  if (lane == 0) { rs[wid] = s; rq[wid] = q; }
  __syncthreads();
  if (tid == 0) {
    float S = rs[0] + rs[1] + rs[2] + rs[3];
    float Q = rq[0] + rq[1] + rq[2] + rq[3];
    float mean = S * (1.f / 1024.f);
    float var = Q * (1.f / 1024.f) - mean * mean;
    stat[0] = mean;
    stat[1] = rsqrtf(var + EPS);
  }
  __syncthreads();
  const float mean = stat[0], rstd = stat[1];
  const int c = tid * 4;
  float4 o4;
  o4.x = (v.x - mean) * rstd * g[c] + bt[c];
  o4.y = (v.y - mean) * rstd * g[c + 1] + bt[c + 1];
  o4.z = (v.z - mean) * rstd * g[c + 2] + bt[c + 2];
  o4.w = (v.w - mean) * rstd * g[c + 3] + bt[c + 3];
  *(float4*)(outF + off) = o4;
  if (MODE == 0) {
    ushort4 ub;
    ub.x = f2bf(o4.x); ub.y = f2bf(o4.y); ub.z = f2bf(o4.z); ub.w = f2bf(o4.w);
    *(ushort4*)(outB + off) = ub;
  }
}

extern "C" void kernel_launch(void* const* d_in, const int* in_sizes, int n_in,
                              void* d_out, int out_size, void* d_ws, size_t ws_size,
                              hipStream_t stream) {
  const float* q    = (const float*)d_in[0];
  const float* wq   = (const float*)d_in[1];
  const float* bq   = (const float*)d_in[2];
  const float* wk   = (const float*)d_in[3];
  const float* bk   = (const float*)d_in[4];
  const float* wv   = (const float*)d_in[5];
  const float* bv   = (const float*)d_in[6];
  const float* wo   = (const float*)d_in[7];
  const float* bo   = (const float*)d_in[8];
  const float* w1   = (const float*)d_in[9];
  const float* bn1g = (const float*)d_in[10];
  const float* bn1b = (const float*)d_in[11];
  const float* bn1m = (const float*)d_in[12];
  const float* bn1v = (const float*)d_in[13];
  const float* w2   = (const float*)d_in[14];
  const float* bn2g = (const float*)d_in[15];
  const float* bn2b = (const float*)d_in[16];
  const float* bn2m = (const float*)d_in[17];
  const float* bn2v = (const float*)d_in[18];
  const float* ln1g = (const float*)d_in[19];
  const float* ln1b = (const float*)d_in[20];
  const float* ln3g = (const float*)d_in[21];
  const float* ln3b = (const float*)d_in[22];

  char* ws = (char*)d_ws;
  const size_t MB = 1u << 20;
  ushort_t* wqkv = (ushort_t*)(ws);            // 6 MB  [3072,1024]
  ushort_t* w1b  = (ushort_t*)(ws + 6 * MB);   // 8 MB  [4096,1024]
  ushort_t* w2b  = (ushort_t*)(ws + 14 * MB);  // 8 MB  [1024,4096]
  ushort_t* wob  = (ushort_t*)(ws + 22 * MB);  // 2 MB  [1024,1024]
  float* sc1 = (float*)(ws + 24 * MB);
  float* sh1 = sc1 + 4096;
  float* sc2 = sh1 + 4096;
  float* sh2 = sc2 + 1024;
  ushort_t* qbf  = (ushort_t*)(ws + 25 * MB);  // 8 MB
  ushort_t* qp   = (ushort_t*)(ws + 33 * MB);  // 8+8+8 MB (qp,kp,vt contiguous)
  ushort_t* aout = (ushort_t*)(ws + 57 * MB);  // 8 MB
  ushort_t* xbf  = (ushort_t*)(ws + 65 * MB);  // 8 MB
  float*    h2   = (float*)(ws + 73 * MB);     // 16 MB
  ushort_t* h1   = (ushort_t*)(ws + 33 * MB);  // 32 MB (reuses qp/kp/vt/aout)
  float* X = (float*)d_out;                    // x lives in d_out (16 MB)

  const int NM = 1024 * 1024;
  cast_all_k<<<8192, 256, 0, stream>>>(wq, wk, wv, wo, w1, w2, q, wqkv, wob, w1b, w2b, qbf);
  bnparam_k<<<20, 256, 0, stream>>>(bn1g, bn1b, bn1m, bn1v, bn2g, bn2b, bn2m, bn2v,
                                    sc1, sh1, sc2, sh2);

  // fused QKV projection: [4096,1024] x [3072,1024]^T, 128x128 dbuf 32x32-MFMA
  gemm32<1024, 0, 2, 2, 2, 2, 256, 24, 32><<<768, 256, 0, stream>>>(
      qbf, wqkv, bq, bk, bv, nullptr, qp);
  // attention (512 blocks x 512 threads, LDS-staged K/V double-buffered)
  attn_k<<<512, 512, 0, stream>>>(qp, qp + 4 * NM, qp + 8 * NM, aout);
  // O projection + bias + residual -> X (f32, in d_out), 128x64 dbuf
  gemm32<1024, 1, 2, 1, 2, 2, 256, 16, 32><<<512, 256, 0, stream>>>(
      aout, wob, bo, q, nullptr, X, nullptr);
  // LN1 -> X (in place) + xbf
  ln_k<0><<<4096, 256, 0, stream>>>(X, nullptr, ln1g, ln1b, X, xbf);
  // MLP1: [4096,1024] x [4096,1024]^T -> BN+GELU(tanh) -> h1 bf16, 256x256 8-wave
  gemm32<1024, 2, 4, 2, 2, 4, 512, 16, 16><<<256, 512, 0, stream>>>(
      xbf, w1b, sc1, sh1, nullptr, nullptr, h1);
  // MLP2: [4096,4096] x [1024,4096]^T -> BN -> h2 f32, 128x64 dbuf
  gemm32<4096, 3, 2, 1, 2, 2, 256, 16, 32><<<512, 256, 0, stream>>>(
      h1, w2b, sc2, sh2, nullptr, h2, nullptr);
  // LN3(X + h2) -> d_out
  ln_k<1><<<4096, 256, 0, stream>>>(X, h2, ln3g, ln3b, X, nullptr);
}

// Round 8
// 209.925 us; speedup vs baseline: 1.0250x; 1.0250x over previous
//
#include <hip/hip_runtime.h>
#include <math.h>

#define EPS 1e-5f

typedef unsigned short ushort_t;
typedef __attribute__((ext_vector_type(8))) __bf16 bf16x8;
typedef __attribute__((ext_vector_type(4))) __bf16 bf16x4;
typedef __attribute__((ext_vector_type(4))) float f32x4;

#define MFMA16(a, b, c) __builtin_amdgcn_mfma_f32_16x16x32_bf16(a, b, c, 0, 0, 0)

// 0.125 (attn scale) * log2(e): folded into Q at the QKV epilogue so the
// attention softmax runs directly in base-2 (v_exp_f32 = 2^x).
#define QSCALE2 0.18033688011112042f

__device__ __forceinline__ unsigned short f2bf(float f) {
  unsigned u = __float_as_uint(f);
  u += 0x7fffu + ((u >> 16) & 1u);
  return (unsigned short)(u >> 16);
}

__device__ __forceinline__ void gload16(const void* g, void* l) {
  __builtin_amdgcn_global_load_lds(
      (__attribute__((address_space(1))) void*)(g),
      (__attribute__((address_space(3))) void*)(l), 16, 0, 0);
}

// ---------------- fused cast f32 -> bf16 for all weights + q ----------------
__global__ __launch_bounds__(256) void cast_all_k(
    const float* __restrict__ wq, const float* __restrict__ wk,
    const float* __restrict__ wv, const float* __restrict__ wo,
    const float* __restrict__ w1, const float* __restrict__ w2,
    const float* __restrict__ q, ushort_t* __restrict__ wqkv,
    ushort_t* __restrict__ wob, ushort_t* __restrict__ w1b,
    ushort_t* __restrict__ w2b, ushort_t* __restrict__ qbf) {
  const int b = blockIdx.x;
  const float* src;
  ushort_t* dst;
  int idx;
  if (b < 2048) {
    const int s = b >> 9;
    src = (s == 0) ? wq : (s == 1) ? wk : (s == 2) ? wv : wo;
    dst = (s == 3) ? wob : wqkv + s * 1048576;
    idx = (b & 511) * 2048 + threadIdx.x * 8;
  } else if (b < 4096) {
    src = w1; dst = w1b; idx = (b - 2048) * 2048 + threadIdx.x * 8;
  } else if (b < 6144) {
    src = w2; dst = w2b; idx = (b - 4096) * 2048 + threadIdx.x * 8;
  } else {
    src = q; dst = qbf; idx = (b - 6144) * 2048 + threadIdx.x * 8;
  }
  float4 a = *(const float4*)(src + idx);
  float4 c = *(const float4*)(src + idx + 4);
  uint4 u;
  u.x = (unsigned)f2bf(a.x) | ((unsigned)f2bf(a.y) << 16);
  u.y = (unsigned)f2bf(a.z) | ((unsigned)f2bf(a.w) << 16);
  u.z = (unsigned)f2bf(c.x) | ((unsigned)f2bf(c.y) << 16);
  u.w = (unsigned)f2bf(c.z) | ((unsigned)f2bf(c.w) << 16);
  *(uint4*)(dst + idx) = u;
}

// ---------------- BN eval params (both BNs in one launch) ----------------
__global__ __launch_bounds__(256) void bnparam_k(
    const float* __restrict__ g1, const float* __restrict__ b1,
    const float* __restrict__ m1, const float* __restrict__ v1,
    const float* __restrict__ g2, const float* __restrict__ b2,
    const float* __restrict__ m2, const float* __restrict__ v2,
    float* __restrict__ sc1, float* __restrict__ sh1,
    float* __restrict__ sc2, float* __restrict__ sh2) {
  int i = blockIdx.x * 256 + threadIdx.x;
  if (i < 4096) {
    float s = g1[i] * rsqrtf(v1[i] + EPS);
    sc1[i] = s;
    sh1[i] = b1[i] - m1[i] * s;
  } else if (i < 5120) {
    int j = i - 4096;
    float s = g2[j] * rsqrtf(v2[j] + EPS);
    sc2[j] = s;
    sh2[j] = b2[j] - m2[j] * s;
  }
}

// ---------------- 2-phase GEMM  C[m,n] = sum_k A[m,k]*W[n,k] ----------------
template <int KDIM, int EPI, int TM, int TN, int WM, int WN, int NTHR, int GX, int GY>
__global__ __launch_bounds__(NTHR, 2) void gemm_bt(const ushort_t* __restrict__ A,
                                                   const ushort_t* __restrict__ W,
                                                   const float* __restrict__ p0,
                                                   const float* __restrict__ p1,
                                                   const float* __restrict__ p2,
                                                   float* __restrict__ outF,
                                                   ushort_t* __restrict__ outB) {
  constexpr int BM = 16 * TM * WM, BN = 16 * TN * WN;
  constexpr int LDS_STAGE = 2 * (BM + BN) * 128;  // bytes, 2 bufs
  constexpr int LDS_TR = (EPI == 0) ? 128 * 136 * 2 : 0;
  __shared__ alignas(16) char pool[(LDS_STAGE > LDS_TR) ? LDS_STAGE : LDS_TR];
  constexpr int LA = BM * 8 / NTHR;  // 16B loads per thread for A tile
  constexpr int LB = BN * 8 / NTHR;

  constexpr int NWG = GX * GY;
  const int id = blockIdx.x;
  const int pos = (id & 7) * (NWG / 8) + (id >> 3);
  const int grp = pos / (8 * GX);
  const int rem = pos % (8 * GX);
  const int by = grp * 8 + (rem & 7);
  const int bx = rem >> 3;
  const int bm = by * BM, bn = bx * BN;

  const int tid = threadIdx.x;
  const int lane = tid & 63;
  const int wid = tid >> 6;
  const int wr = wid / WN, wc = wid % WN;
  const int fr = lane & 15;
  const int kg = lane >> 4;

  const char* Ag0 = (const char*)(A + (size_t)bm * KDIM);
  const char* Bg0 = (const char*)(W + (size_t)bn * KDIM);

#define STAGE(bufi, t_)                                                        \
  do {                                                                         \
    const char* Ag = Ag0 + (size_t)(t_)*128;                                   \
    const char* Bg = Bg0 + (size_t)(t_)*128;                                   \
    char* Ab = pool + (bufi) * (BM * 128);                                     \
    char* Bb = pool + 2 * BM * 128 + (bufi) * (BN * 128);                      \
    _Pragma("unroll") for (int li = 0; li < LA; ++li) {                        \
      const int f = li * NTHR + tid;                                           \
      const int row = f >> 3;                                                  \
      const int gl = (f & 7) ^ (row & 7);                                      \
      gload16(Ag + (size_t)row * (KDIM * 2) + gl * 16,                         \
              Ab + (li * NTHR + wid * 64) * 16);                               \
    }                                                                          \
    _Pragma("unroll") for (int li = 0; li < LB; ++li) {                        \
      const int f = li * NTHR + tid;                                           \
      const int row = f >> 3;                                                  \
      const int gl = (f & 7) ^ (row & 7);                                      \
      gload16(Bg + (size_t)row * (KDIM * 2) + gl * 16,                         \
              Bb + (li * NTHR + wid * 64) * 16);                               \
    }                                                                          \
  } while (0)

  f32x4 acc[TM][TN];
#pragma unroll
  for (int i = 0; i < TM; ++i)
#pragma unroll
    for (int j = 0; j < TN; ++j)
#pragma unroll
      for (int r = 0; r < 4; ++r) acc[i][j][r] = 0.f;

  STAGE(0, 0);
  asm volatile("s_waitcnt vmcnt(0)" ::: "memory");
  __builtin_amdgcn_s_barrier();

  constexpr int NT = KDIM / 64;
  for (int t = 0; t < NT; ++t) {
    const int b = t & 1;
    if (t + 1 < NT) STAGE(b ^ 1, t + 1);  // prefetch flies under compute
    const char* Ac = pool + b * (BM * 128);
    const char* Bc = pool + 2 * BM * 128 + b * (BN * 128);
#pragma unroll
    for (int s = 0; s < 2; ++s) {
      bf16x8 bfv[TN];
#pragma unroll
      for (int nf = 0; nf < TN; ++nf) {
        const int row = wc * (16 * TN) + nf * 16 + fr;
        bfv[nf] = *(const bf16x8*)(Bc + row * 128 + (((s * 4 + kg) ^ (row & 7)) * 16));
      }
#pragma unroll
      for (int mf = 0; mf < TM; ++mf) {
        const int row = wr * (16 * TM) + mf * 16 + fr;
        bf16x8 af = *(const bf16x8*)(Ac + row * 128 + (((s * 4 + kg) ^ (row & 7)) * 16));
#pragma unroll
        for (int nf = 0; nf < TN; ++nf) acc[mf][nf] = MFMA16(af, bfv[nf], acc[mf][nf]);
      }
    }
    asm volatile("s_waitcnt vmcnt(0)" ::: "memory");
    __builtin_amdgcn_s_barrier();
  }
#undef STAGE

  if constexpr (EPI == 0) {
    if (bn < 2048) {
#pragma unroll
      for (int mf = 0; mf < TM; ++mf) {
#pragma unroll
        for (int nf = 0; nf < TN; ++nf) {
#pragma unroll
          for (int r = 0; r < 4; ++r) {
            const int m = bm + wr * (16 * TM) + mf * 16 + kg * 4 + r;
            const int n = bn + wc * (16 * TN) + nf * 16 + fr;
            const int sel = n >> 10;
            const int nl = n & 1023;
            float v = acc[mf][nf][r] + ((sel == 0) ? p0[nl] : p1[nl]);
            if (sel == 0) v *= QSCALE2;
            const int b_ = m >> 10, tok = m & 1023;
            const int h_ = nl >> 6, d_ = nl & 63;
            outB[(size_t)sel * 4194304 + (((size_t)(b_ * 16 + h_) * 1024 + tok) * 64 + d_)] =
                f2bf(v);
          }
        }
      }
    } else {
      __syncthreads();
      ushort_t* T = (ushort_t*)pool;  // [128 n][136 m-pad]
#pragma unroll
      for (int mf = 0; mf < TM; ++mf) {
#pragma unroll
        for (int nf = 0; nf < TN; ++nf) {
          const int ml = wr * (16 * TM) + mf * 16 + kg * 4;
          const int nl = wc * (16 * TN) + nf * 16 + fr;
          const float bias = p2[(bn & 1023) + nl];
          bf16x4 pw;
#pragma unroll
          for (int r = 0; r < 4; ++r) pw[r] = (__bf16)(acc[mf][nf][r] + bias);
          *(bf16x4*)(T + nl * 136 + ml) = pw;
        }
      }
      __syncthreads();
      const int b_ = bm >> 10;
      const int tokb = bm & 1023;
#pragma unroll
      for (int it = 0; it < 8; ++it) {
        const int g = it * 256 + tid;
        const int nl = g >> 4;
        const int m0 = (g & 15) * 8;
        bf16x8 v = *(const bf16x8*)(T + nl * 136 + m0);
        const int nloc = (bn - 2048) + nl;
        const int h_ = nloc >> 6, d_ = nloc & 63;
        *(bf16x8*)(outB + 8388608 + (((size_t)(b_ * 16 + h_) * 64 + d_) << 10) + tokb + m0) = v;
      }
    }
  } else {
#pragma unroll
    for (int mf = 0; mf < TM; ++mf) {
#pragma unroll
      for (int nf = 0; nf < TN; ++nf) {
#pragma unroll
        for (int r = 0; r < 4; ++r) {
          const int m = bm + wr * (16 * TM) + mf * 16 + kg * 4 + r;
          const int n = bn + wc * (16 * TN) + nf * 16 + fr;
          float v = acc[mf][nf][r];
          if constexpr (EPI == 1) {
            v += p0[n] + p1[(size_t)m * 1024 + n];
            outF[(size_t)m * 1024 + n] = v;
          } else if constexpr (EPI == 2) {
            // tanh-form GELU (|err| vs exact erf <= ~3e-3)
            float tt = v * p0[n] + p1[n];
            float u = tt * (0.7978845608f + 0.0356774081f * tt * tt);
            float e = exp2f(u * 2.8853900818f);  // e^{2u}
            float ge = tt * (1.f - 1.f / (e + 1.f));
            outB[(size_t)m * 4096 + n] = f2bf(ge);
          } else {
            outF[(size_t)m * 1024 + n] = v * p0[n] + p1[n];
          }
        }
      }
    }
  }
}

// ---------------- 3-stage counted-vmcnt GEMM (MLP2: BN -> f32) ----------------
// 128x64 tile, 4 waves (2x2), 3 LDS buffers, 2-tiles-ahead prefetch. The wait
// before each barrier is vmcnt(LA+LB)=6 (newest stage stays in flight across
// the barrier) instead of the 2-phase drain-to-0 -- T4's counted-wait applied
// minimally. Buffer hazards: stage(t+2) targets buf[(t-1)%3], last read in
// iter t-1 and fenced by that iteration's barrier; compute(t) reads the buffer
// drained by iter t-1's vmcnt(6)+barrier.
template <int KDIM, int TM, int TN, int GX, int GY>
__global__ __launch_bounds__(256, 2) void gemm3s(const ushort_t* __restrict__ A,
                                                 const ushort_t* __restrict__ W,
                                                 const float* __restrict__ sc,
                                                 const float* __restrict__ sh,
                                                 float* __restrict__ outF) {
  constexpr int BM = 32 * TM, BN = 32 * TN;
  __shared__ alignas(16) char pool[3 * (BM + BN) * 128];
  constexpr int LA = BM * 8 / 256;
  constexpr int LB = BN * 8 / 256;

  constexpr int NWG = GX * GY;
  const int id = blockIdx.x;
  const int pos = (id & 7) * (NWG / 8) + (id >> 3);
  const int grp = pos / (8 * GX);
  const int rem = pos % (8 * GX);
  const int by = grp * 8 + (rem & 7);
  const int bx = rem >> 3;
  const int bm = by * BM, bn = bx * BN;

  const int tid = threadIdx.x;
  const int lane = tid & 63;
  const int wid = tid >> 6;
  const int wr = wid >> 1, wc = wid & 1;
  const int fr = lane & 15;
  const int kg = lane >> 4;

  const char* Ag0 = (const char*)(A + (size_t)bm * KDIM);
  const char* Bg0 = (const char*)(W + (size_t)bn * KDIM);

#define STAGE3(bufi, t_)                                                       \
  do {                                                                         \
    const char* Ag = Ag0 + (size_t)(t_)*128;                                   \
    const char* Bg = Bg0 + (size_t)(t_)*128;                                   \
    char* Ab = pool + (bufi) * (BM * 128);                                     \
    char* Bb = pool + 3 * BM * 128 + (bufi) * (BN * 128);                      \
    _Pragma("unroll") for (int li = 0; li < LA; ++li) {                        \
      const int f = li * 256 + tid;                                            \
      const int row = f >> 3;                                                  \
      const int gl = (f & 7) ^ (row & 7);                                      \
      gload16(Ag + (size_t)row * (KDIM * 2) + gl * 16,                         \
              Ab + (li * 256 + wid * 64) * 16);                                \
    }                                                                          \
    _Pragma("unroll") for (int li = 0; li < LB; ++li) {                        \
      const int f = li * 256 + tid;                                            \
      const int row = f >> 3;                                                  \
      const int gl = (f & 7) ^ (row & 7);                                      \
      gload16(Bg + (size_t)row * (KDIM * 2) + gl * 16,                         \
              Bb + (li * 256 + wid * 64) * 16);                                \
    }                                                                          \
  } while (0)

  f32x4 acc[TM][TN];
#pragma unroll
  for (int i = 0; i < TM; ++i)
#pragma unroll
    for (int j = 0; j < TN; ++j)
#pragma unroll
      for (int r = 0; r < 4; ++r) acc[i][j][r] = 0.f;

  STAGE3(0, 0);
  STAGE3(1, 1);
  asm volatile("s_waitcnt vmcnt(6)" ::: "memory");  // stage(0) drained
  __builtin_amdgcn_s_barrier();

  constexpr int NT = KDIM / 64;
  int cb = 0;
  for (int t = 0; t < NT; ++t) {
    if (t + 2 < NT) {
      const int nb = (cb + 2 >= 3) ? cb - 1 : cb + 2;
      STAGE3(nb, t + 2);
    }
    const char* Ac = pool + cb * (BM * 128);
    const char* Bc = pool + 3 * BM * 128 + cb * (BN * 128);
#pragma unroll
    for (int s = 0; s < 2; ++s) {
      bf16x8 bfv[TN];
#pragma unroll
      for (int nf = 0; nf < TN; ++nf) {
        const int row = wc * (16 * TN) + nf * 16 + fr;
        bfv[nf] = *(const bf16x8*)(Bc + row * 128 + (((s * 4 + kg) ^ (row & 7)) * 16));
      }
#pragma unroll
      for (int mf = 0; mf < TM; ++mf) {
        const int row = wr * (16 * TM) + mf * 16 + fr;
        bf16x8 af = *(const bf16x8*)(Ac + row * 128 + (((s * 4 + kg) ^ (row & 7)) * 16));
#pragma unroll
        for (int nf = 0; nf < TN; ++nf) acc[mf][nf] = MFMA16(af, bfv[nf], acc[mf][nf]);
      }
    }
    if (t + 2 < NT)
      asm volatile("s_waitcnt vmcnt(6)" ::: "memory");  // drain stage(t+1) only
    else
      asm volatile("s_waitcnt vmcnt(0)" ::: "memory");  // tail: full drain
    asm volatile("s_waitcnt lgkmcnt(0)" ::: "memory");
    __builtin_amdgcn_s_barrier();
    cb = (cb + 1 >= 3) ? 0 : cb + 1;
  }
#undef STAGE3

#pragma unroll
  for (int mf = 0; mf < TM; ++mf) {
#pragma unroll
    for (int nf = 0; nf < TN; ++nf) {
      const int n = bn + wc * (16 * TN) + nf * 16 + fr;
      const float scn = sc[n], shn = sh[n];
#pragma unroll
      for (int r = 0; r < 4; ++r) {
        const int m = bm + wr * (16 * TM) + mf * 16 + kg * 4 + r;
        outF[(size_t)m * 1024 + n] = acc[mf][nf][r] * scn + shn;
      }
    }
  }
}

// ---------------- flash attention (swapped QK^T, LDS-staged K/V, dbuf) -------
__global__ __launch_bounds__(512) void attn_k(const ushort_t* __restrict__ qp,
                                              const ushort_t* __restrict__ kp,
                                              const ushort_t* __restrict__ vt,
                                              ushort_t* __restrict__ aout) {
  __shared__ ushort_t Kt[2][4096];
  __shared__ ushort_t Vt[2][4096];
  __shared__ ushort_t P[8][16][72];
  const int tid = threadIdx.x;
  const int lane = tid & 63;
  const int wid = tid >> 6;
  const int fr = lane & 15;
  const int kg = lane >> 4;
  const int id = blockIdx.x;
  const int slot = id >> 3;
  const int bh = ((id & 7) << 3) | (slot >> 3);  // 8 heads per XCD chunk
  const int qc = slot & 7;
  const int b_ = bh >> 4, h_ = bh & 15;

  const size_t base = (size_t)bh << 10;
  const int qrow = qc * 128 + wid * 16 + fr;
  bf16x8 qf0 = *(const bf16x8*)(qp + ((base + qrow) << 6) + kg * 8);
  bf16x8 qf1 = *(const bf16x8*)(qp + ((base + qrow) << 6) + 32 + kg * 8);

  const int srow = tid >> 3;
  const int sg16 = ((tid & 7) ^ (srow & 7)) * 16;
  const char* kTileB = (const char*)kp + ((size_t)bh << 17);
  const char* vTileB = (const char*)vt + ((size_t)bh << 17);
  const size_t koff = (size_t)srow * 128 + sg16;   // + kt*8192
  const size_t voff = (size_t)srow * 2048 + sg16;  // + kt*128

#define STAGE(bufi, kt_)                                                      \
  do {                                                                        \
    gload16(kTileB + (size_t)(kt_)*8192 + koff, (char*)Kt[bufi] + wid * 1024); \
    gload16(vTileB + (size_t)(kt_)*128 + voff, (char*)Vt[bufi] + wid * 1024);  \
  } while (0)

  f32x4 oacc[4];
#pragma unroll
  for (int d = 0; d < 4; ++d)
#pragma unroll
    for (int r = 0; r < 4; ++r) oacc[d][r] = 0.f;
  float mrun = -3.0e38f, lrun = 0.f;

  STAGE(0, 0);
  __syncthreads();

  for (int kt = 0; kt < 16; ++kt) {
    const int c = kt & 1;
    if (kt < 15) STAGE(c ^ 1, kt + 1);
    const char* Kc = (const char*)Kt[c];
    const char* Vc = (const char*)Vt[c];

    f32x4 sacc[4];
#pragma unroll
    for (int nf = 0; nf < 4; ++nf)
#pragma unroll
      for (int r = 0; r < 4; ++r) sacc[nf][r] = 0.f;
    __builtin_amdgcn_s_setprio(1);
#pragma unroll
    for (int nf = 0; nf < 4; ++nf) {
      const int r_ = nf * 16 + fr;
      const char* kr = Kc + r_ * 128;
      bf16x8 kf0 = *(const bf16x8*)(kr + ((kg ^ (r_ & 7)) * 16));
      bf16x8 kf1 = *(const bf16x8*)(kr + (((kg + 4) ^ (r_ & 7)) * 16));
      sacc[nf] = MFMA16(kf0, qf0, sacc[nf]);
      sacc[nf] = MFMA16(kf1, qf1, sacc[nf]);
    }
    __builtin_amdgcn_s_setprio(0);
    float mx = sacc[0][0];
#pragma unroll
    for (int nf = 0; nf < 4; ++nf)
#pragma unroll
      for (int r = 0; r < 4; ++r) mx = fmaxf(mx, sacc[nf][r]);
    mx = fmaxf(mx, __shfl_xor(mx, 16));
    mx = fmaxf(mx, __shfl_xor(mx, 32));
    const float mn = fmaxf(mrun, mx);
    const float c_ = exp2f(mrun - mn);
    float rs = 0.f;
#pragma unroll
    for (int nf = 0; nf < 4; ++nf) {
      bf16x4 pw;
#pragma unroll
      for (int r = 0; r < 4; ++r) {
        float ev = exp2f(sacc[nf][r] - mn);
        rs += ev;
        pw[r] = (__bf16)ev;
      }
      *(bf16x4*)(&P[wid][fr][nf * 16 + kg * 4]) = pw;
    }
    rs += __shfl_xor(rs, 16);
    rs += __shfl_xor(rs, 32);
    lrun = lrun * c_ + rs;
    mrun = mn;
    float cb[4];
#pragma unroll
    for (int r = 0; r < 4; ++r) cb[r] = __shfl(c_, kg * 4 + r);
#pragma unroll
    for (int d = 0; d < 4; ++d)
#pragma unroll
      for (int r = 0; r < 4; ++r) oacc[d][r] *= cb[r];
    bf16x8 pa0 = *(const bf16x8*)(&P[wid][fr][kg * 8]);
    bf16x8 pa1 = *(const bf16x8*)(&P[wid][fr][32 + kg * 8]);
    __builtin_amdgcn_s_setprio(1);
#pragma unroll
    for (int df = 0; df < 4; ++df) {
      const int r_ = df * 16 + fr;
      const char* vr_ = Vc + r_ * 128;
      bf16x8 vf0 = *(const bf16x8*)(vr_ + ((kg ^ (r_ & 7)) * 16));
      bf16x8 vf1 = *(const bf16x8*)(vr_ + (((kg + 4) ^ (r_ & 7)) * 16));
      oacc[df] = MFMA16(pa0, vf0, oacc[df]);
      oacc[df] = MFMA16(pa1, vf1, oacc[df]);
    }
    __builtin_amdgcn_s_setprio(0);
    __syncthreads();
  }
#undef STAGE

  float linv[4];
#pragma unroll
  for (int r = 0; r < 4; ++r) linv[r] = 1.f / __shfl(lrun, kg * 4 + r);
#pragma unroll
  for (int df = 0; df < 4; ++df) {
#pragma unroll
    for (int r = 0; r < 4; ++r) {
      const int tok = qc * 128 + wid * 16 + kg * 4 + r;
      const int d_ = df * 16 + fr;
      aout[((size_t)(b_ * 1024 + tok) * 16 + h_) * 64 + d_] = f2bf(oacc[df][r] * linv[r]);
    }
  }
}

// ---------------- LayerNorm over rows of 1024 ----------------
template <int MODE>
__global__ __launch_bounds__(256) void ln_k(const float* __restrict__ in1,
                                            const float* __restrict__ in2,
                                            const float* __restrict__ g,
                                            const float* __restrict__ bt,
                                            float* __restrict__ outF,
                                            ushort_t* __restrict__ outB) {
  const int row = blockIdx.x;
  const int tid = threadIdx.x;
  const size_t off = (size_t)row * 1024 + tid * 4;
  float4 v = *(const float4*)(in1 + off);
  if (MODE == 1) {
    float4 u = *(const float4*)(in2 + off);
    v.x += u.x; v.y += u.y; v.z += u.z; v.w += u.w;
  }
  float s = v.x + v.y + v.z + v.w;
  float q = v.x * v.x + v.y * v.y + v.z * v.z + v.w * v.w;
#pragma unroll
  for (int o = 32; o > 0; o >>= 1) {
    s += __shfl_down(s, o);
    q += __shfl_down(q, o);
  }
  __shared__ float rs[4], rq[4], stat[2];
  const int wid = tid >> 6, lane = tid & 63;
  if (lane == 0) { rs[wid] = s; rq[wid] = q; }
  __syncthreads();
  if (tid == 0) {
    float S = rs[0] + rs[1] + rs[2] + rs[3];
    float Q = rq[0] + rq[1] + rq[2] + rq[3];
    float mean = S * (1.f / 1024.f);
    float var = Q * (1.f / 1024.f) - mean * mean;
    stat[0] = mean;
    stat[1] = rsqrtf(var + EPS);
  }
  __syncthreads();
  const float mean = stat[0], rstd = stat[1];
  const int c = tid * 4;
  float4 o4;
  o4.x = (v.x - mean) * rstd * g[c] + bt[c];
  o4.y = (v.y - mean) * rstd * g[c + 1] + bt[c + 1];
  o4.z = (v.z - mean) * rstd * g[c + 2] + bt[c + 2];
  o4.w = (v.w - mean) * rstd * g[c + 3] + bt[c + 3];
  *(float4*)(outF + off) = o4;
  if (MODE == 0) {
    ushort4 ub;
    ub.x = f2bf(o4.x); ub.y = f2bf(o4.y); ub.z = f2bf(o4.z); ub.w = f2bf(o4.w);
    *(ushort4*)(outB + off) = ub;
  }
}

extern "C" void kernel_launch(void* const* d_in, const int* in_sizes, int n_in,
                              void* d_out, int out_size, void* d_ws, size_t ws_size,
                              hipStream_t stream) {
  const float* q    = (const float*)d_in[0];
  const float* wq   = (const float*)d_in[1];
  const float* bq   = (const float*)d_in[2];
  const float* wk   = (const float*)d_in[3];
  const float* bk   = (const float*)d_in[4];
  const float* wv   = (const float*)d_in[5];
  const float* bv   = (const float*)d_in[6];
  const float* wo   = (const float*)d_in[7];
  const float* bo   = (const float*)d_in[8];
  const float* w1   = (const float*)d_in[9];
  const float* bn1g = (const float*)d_in[10];
  const float* bn1b = (const float*)d_in[11];
  const float* bn1m = (const float*)d_in[12];
  const float* bn1v = (const float*)d_in[13];
  const float* w2   = (const float*)d_in[14];
  const float* bn2g = (const float*)d_in[15];
  const float* bn2b = (const float*)d_in[16];
  const float* bn2m = (const float*)d_in[17];
  const float* bn2v = (const float*)d_in[18];
  const float* ln1g = (const float*)d_in[19];
  const float* ln1b = (const float*)d_in[20];
  const float* ln3g = (const float*)d_in[21];
  const float* ln3b = (const float*)d_in[22];

  char* ws = (char*)d_ws;
  const size_t MB = 1u << 20;
  ushort_t* wqkv = (ushort_t*)(ws);            // 6 MB  [3072,1024]
  ushort_t* w1b  = (ushort_t*)(ws + 6 * MB);   // 8 MB  [4096,1024]
  ushort_t* w2b  = (ushort_t*)(ws + 14 * MB);  // 8 MB  [1024,4096]
  ushort_t* wob  = (ushort_t*)(ws + 22 * MB);  // 2 MB  [1024,1024]
  float* sc1 = (float*)(ws + 24 * MB);
  float* sh1 = sc1 + 4096;
  float* sc2 = sh1 + 4096;
  float* sh2 = sc2 + 1024;
  ushort_t* qbf  = (ushort_t*)(ws + 25 * MB);  // 8 MB
  ushort_t* qp   = (ushort_t*)(ws + 33 * MB);  // 8+8+8 MB (qp,kp,vt contiguous)
  ushort_t* aout = (ushort_t*)(ws + 57 * MB);  // 8 MB
  ushort_t* xbf  = (ushort_t*)(ws + 65 * MB);  // 8 MB
  float*    h2   = (float*)(ws + 73 * MB);     // 16 MB
  ushort_t* h1   = (ushort_t*)(ws + 33 * MB);  // 32 MB (reuses qp/kp/vt/aout)
  float* X = (float*)d_out;                    // x lives in d_out (16 MB)

  const int NM = 1024 * 1024;
  cast_all_k<<<8192, 256, 0, stream>>>(wq, wk, wv, wo, w1, w2, q, wqkv, wob, w1b, w2b, qbf);
  bnparam_k<<<20, 256, 0, stream>>>(bn1g, bn1b, bn1m, bn1v, bn2g, bn2b, bn2m, bn2v,
                                    sc1, sh1, sc2, sh2);

  // fused QKV projection: [4096,1024] x [3072,1024]^T, 128x128 dbuf
  gemm_bt<1024, 0, 4, 4, 2, 2, 256, 24, 32><<<768, 256, 0, stream>>>(
      qbf, wqkv, bq, bk, bv, nullptr, qp);
  // attention (512 blocks x 512 threads, LDS-staged K/V double-buffered)
  attn_k<<<512, 512, 0, stream>>>(qp, qp + 4 * NM, qp + 8 * NM, aout);
  // O projection + bias + residual -> X (f32, in d_out), 128x64 dbuf
  gemm_bt<1024, 1, 4, 2, 2, 2, 256, 16, 32><<<512, 256, 0, stream>>>(
      aout, wob, bo, q, nullptr, X, nullptr);
  // LN1 -> X (in place) + xbf
  ln_k<0><<<4096, 256, 0, stream>>>(X, nullptr, ln1g, ln1b, X, xbf);
  // MLP1: [4096,1024] x [4096,1024]^T -> BN+GELU(tanh) -> h1 bf16, 256x256 8-wave dbuf
  gemm_bt<1024, 2, 8, 4, 2, 4, 512, 16, 16><<<256, 512, 0, stream>>>(
      xbf, w1b, sc1, sh1, nullptr, nullptr, h1);
  // MLP2: [4096,4096] x [1024,4096]^T -> BN -> h2 f32, 128x64 3-stage counted-vmcnt
  gemm3s<4096, 4, 2, 16, 32><<<512, 256, 0, stream>>>(h1, w2b, sc2, sh2, h2);
  // LN3(X + h2) -> d_out
  ln_k<1><<<4096, 256, 0, stream>>>(X, h2, ln3g, ln3b, X, nullptr);
}